// Round 2
// baseline (162.892 us; speedup 1.0000x reference)
//
#include <hip/hip_runtime.h>
#include <hip/hip_bf16.h>
#include <cstdint>
#include <cstddef>

typedef __attribute__((ext_vector_type(8))) short bf16x8;
typedef __attribute__((ext_vector_type(4))) float f32x4;
typedef unsigned int u32;
typedef unsigned short u16;

__device__ __forceinline__ u16 f2bf(float f) {
  union { float f; u32 u; } v; v.f = f;
  u32 r = v.u + 0x7FFFu + ((v.u >> 16) & 1u);   // round-nearest-even
  return (u16)(r >> 16);
}
__device__ __forceinline__ u32 pk2(float a, float b) {
  return (u32)f2bf(a) | ((u32)f2bf(b) << 16);
}

// ---------------------------------------------------------------------------
// Kernel 1: pe bilinear upsample (half-pixel, clamp) + xp = x + 0.025*pe.
// Writes xp f32 [b][c][n] and xpT bf16 [b][n][c] (LDS transpose).
// Tile: 64 c x 64 n. Note n0 is 64-aligned -> h constant per block.
// ---------------------------------------------------------------------------
__global__ __launch_bounds__(256) void k_prep(const float* __restrict__ x,
                                              const float* __restrict__ pos,
                                              float* __restrict__ xp,
                                              u16* __restrict__ xpT) {
  __shared__ float tile[64][65];
  int t = threadIdx.x;
  int n0 = blockIdx.x * 64;
  int c0 = blockIdx.y * 64;
  int bb = blockIdx.z;
  int h = n0 >> 6;
  float sy = 0.5f * (float)h - 0.25f;
  int y0 = (int)floorf(sy);
  float fy = sy - (float)y0;
  int y0c = y0 < 0 ? 0 : y0;
  int y1c = (y0 + 1 > 31) ? 31 : y0 + 1;

  int cl = t >> 2, nq = t & 3;
  int c = c0 + cl;
  const float* pr0 = pos + (size_t)c * 1024 + y0c * 32;
  const float* pr1 = pos + (size_t)c * 1024 + y1c * 32;
  size_t gbase = ((size_t)(bb * 128 + c)) * 4096 + n0;
#pragma unroll
  for (int u = 0; u < 4; ++u) {
    int nl = nq * 16 + u * 4;
    float4 xv = *(const float4*)(x + gbase + nl);
    float vals[4] = {xv.x, xv.y, xv.z, xv.w};
#pragma unroll
    for (int j = 0; j < 4; ++j) {
      int w = nl + j;                      // w coord (h fixed per block)
      float sx = 0.5f * (float)w - 0.25f;
      int xi = (int)floorf(sx);
      float fx = sx - (float)xi;
      int x0c = xi < 0 ? 0 : xi;
      int x1c = (xi + 1 > 31) ? 31 : xi + 1;
      float top = (1.f - fx) * pr0[x0c] + fx * pr0[x1c];
      float bot = (1.f - fx) * pr1[x0c] + fx * pr1[x1c];
      float pe = (1.f - fy) * top + fy * bot;
      float xe = vals[j] + 0.025f * pe;    // scale_factor(0.25)*0.1
      vals[j] = xe;
      tile[cl][nl + j] = xe;
    }
    float4 st = {vals[0], vals[1], vals[2], vals[3]};
    *(float4*)(xp + gbase + nl) = st;
  }
  __syncthreads();
  // transpose out: thread -> one n row, 16 c values
  int nl = t & 63, qr = t >> 6;
  int n = n0 + nl;
  u32 wbuf[8];
#pragma unroll
  for (int p = 0; p < 8; ++p)
    wbuf[p] = pk2(tile[qr * 16 + 2 * p][nl], tile[qr * 16 + 2 * p + 1][nl]);
  size_t tb = (((size_t)bb * 4096) + n) * 128 + c0 + qr * 16;
  uint4 w0 = {wbuf[0], wbuf[1], wbuf[2], wbuf[3]};
  uint4 w1 = {wbuf[4], wbuf[5], wbuf[6], wbuf[7]};
  *(uint4*)(xpT + tb) = w0;
  *(uint4*)(xpT + tb + 8) = w1;
}

// ---------------------------------------------------------------------------
// Kernel 2: concat weights -> bf16 [192][128], bias -> f32 [192]
// rows 0-31 = Wq, 32-63 = Wk, 64-191 = Wv
// ---------------------------------------------------------------------------
__global__ __launch_bounds__(256) void k_wcat(const float* __restrict__ Wq,
    const float* __restrict__ bq, const float* __restrict__ Wk,
    const float* __restrict__ bk, const float* __restrict__ Wv,
    const float* __restrict__ bv, u16* __restrict__ wc, float* __restrict__ bc) {
  int idx = blockIdx.x * 256 + threadIdx.x;
  if (idx < 24576) {
    int row = idx >> 7, col = idx & 127;
    float v = row < 32 ? Wq[row * 128 + col]
            : row < 64 ? Wk[(row - 32) * 128 + col]
                       : Wv[(row - 64) * 128 + col];
    wc[idx] = f2bf(v);
  }
  if (idx < 192)
    bc[idx] = idx < 32 ? bq[idx] : idx < 64 ? bk[idx - 32] : bv[idx - 64];
}

// ---------------------------------------------------------------------------
// Kernel 3: projection GEMM: out(192 x 4096) = Wcat(192x128) * xpT^T per batch.
// Block = 4 waves, block tile = 192 x 64 (wave: 3 m-tiles x 4 n-tiles).
// q,k -> [b][n][32] bf16; v -> [b][c][n] bf16 (transposed store).
// ---------------------------------------------------------------------------
__global__ __launch_bounds__(256) void k_proj(const u16* __restrict__ xpT,
    const u16* __restrict__ wc, const float* __restrict__ bc,
    u16* __restrict__ qw, u16* __restrict__ kw, u16* __restrict__ vw) {
  int t = threadIdx.x;
  int wv = t >> 6, lane = t & 63, li = lane & 15, g = lane >> 4;
  int n0 = blockIdx.x * 64;
  int b = blockIdx.y;
  f32x4 acc[3][4];
#pragma unroll
  for (int s = 0; s < 3; ++s)
#pragma unroll
    for (int nt = 0; nt < 4; ++nt) acc[s][nt] = (f32x4){0.f, 0.f, 0.f, 0.f};
#pragma unroll
  for (int kc = 0; kc < 4; ++kc) {
    bf16x8 af[3], bfr[4];
#pragma unroll
    for (int s = 0; s < 3; ++s)
      af[s] = *(const bf16x8*)(wc + ((wv * 3 + s) * 16 + li) * 128 + kc * 32 + g * 8);
#pragma unroll
    for (int nt = 0; nt < 4; ++nt)
      bfr[nt] = *(const bf16x8*)(xpT + (((size_t)b * 4096) + n0 + nt * 16 + li) * 128 + kc * 32 + g * 8);
#pragma unroll
    for (int s = 0; s < 3; ++s)
#pragma unroll
      for (int nt = 0; nt < 4; ++nt)
        acc[s][nt] = __builtin_amdgcn_mfma_f32_16x16x32_bf16(af[s], bfr[nt], acc[s][nt], 0, 0, 0);
  }
#pragma unroll
  for (int s = 0; s < 3; ++s) {
    int mts = wv * 3 + s;
    int ob = mts * 16 + g * 4;        // output-channel base for this lane's rows
    float bias[4];
#pragma unroll
    for (int r = 0; r < 4; ++r) bias[r] = bc[ob + r];
#pragma unroll
    for (int nt = 0; nt < 4; ++nt) {
      int n = n0 + nt * 16 + li;
      float v0 = acc[s][nt][0] + bias[0];
      float v1 = acc[s][nt][1] + bias[1];
      float v2 = acc[s][nt][2] + bias[2];
      float v3 = acc[s][nt][3] + bias[3];
      if (mts < 2) {
        uint2 pk; pk.x = pk2(v0, v1); pk.y = pk2(v2, v3);
        *(uint2*)(qw + (((size_t)b * 4096) + n) * 32 + ob) = pk;
      } else if (mts < 4) {
        uint2 pk; pk.x = pk2(v0, v1); pk.y = pk2(v2, v3);
        *(uint2*)(kw + (((size_t)b * 4096) + n) * 32 + (ob - 32)) = pk;
      } else {
        int cv = ob - 64;
        vw[(((size_t)b * 128) + cv + 0) * 4096 + n] = f2bf(v0);
        vw[(((size_t)b * 128) + cv + 1) * 4096 + n] = f2bf(v1);
        vw[(((size_t)b * 128) + cv + 2) * 4096 + n] = f2bf(v2);
        vw[(((size_t)b * 128) + cv + 3) * 4096 + n] = f2bf(v3);
      }
    }
  }
}

// ---------------------------------------------------------------------------
// Kernel 4: flash attention, 1 wave = 16 q-rows, KV chunk = 32.
// Swapped QK^T: S^T = mfma(K_tile, Q) -> lane owns q-row i=li, j = g*4+r (+16).
// O^T accumulated as 8 c-tiles: ot[ct] holds O[i=li][c = ct*16+g*4+r].
// No LDS, no barriers; K/V fragment loads hit L2.
// ---------------------------------------------------------------------------
__global__ __launch_bounds__(256) void k_attn(const u16* __restrict__ qw,
    const u16* __restrict__ kw, const u16* __restrict__ vw,
    const float* __restrict__ xp, const float* __restrict__ gamma,
    float* __restrict__ out) {
  int t = threadIdx.x;
  int wv = t >> 6, lane = t & 63, li = lane & 15, g = lane >> 4;
  int b = blockIdx.y;
  int q0 = blockIdx.x * 64 + wv * 16;
  const float scale = 0.088388347648318447f;   // 1/(sqrt(128)+1e-8)
  bf16x8 qf = *(const bf16x8*)(qw + (((size_t)b * 4096) + q0 + li) * 32 + g * 8);
  f32x4 ot[8];
#pragma unroll
  for (int ct = 0; ct < 8; ++ct) ot[ct] = (f32x4){0.f, 0.f, 0.f, 0.f};
  float m_run = -1e30f, l_run = 0.f;
  const f32x4 zz = {0.f, 0.f, 0.f, 0.f};
  const u16* kbb = kw + ((size_t)b * 4096) * 32;
  const u16* vbb = vw + ((size_t)b * 128) * 4096;

  for (int kv0 = 0; kv0 < 4096; kv0 += 32) {
    bf16x8 kf0 = *(const bf16x8*)(kbb + (size_t)(kv0 + li) * 32 + g * 8);
    bf16x8 kf1 = *(const bf16x8*)(kbb + (size_t)(kv0 + 16 + li) * 32 + g * 8);
    f32x4 st0 = __builtin_amdgcn_mfma_f32_16x16x32_bf16(kf0, qf, zz, 0, 0, 0);
    f32x4 st1 = __builtin_amdgcn_mfma_f32_16x16x32_bf16(kf1, qf, zz, 0, 0, 0);
    float x0[4], x1[4];
#pragma unroll
    for (int r = 0; r < 4; ++r) { x0[r] = st0[r] * scale; x1[r] = st1[r] * scale; }
    float mx = fmaxf(fmaxf(fmaxf(x0[0], x0[1]), fmaxf(x0[2], x0[3])),
                     fmaxf(fmaxf(x1[0], x1[1]), fmaxf(x1[2], x1[3])));
    mx = fmaxf(mx, __shfl_xor(mx, 16));
    mx = fmaxf(mx, __shfl_xor(mx, 32));
    float mnew = fmaxf(m_run, mx);
    float alpha = __expf(m_run - mnew);
    float p0[4], p1[4];
    float sum = 0.f;
#pragma unroll
    for (int r = 0; r < 4; ++r) {
      p0[r] = __expf(x0[r] - mnew);
      p1[r] = __expf(x1[r] - mnew);
      sum += p0[r] + p1[r];
    }
    sum += __shfl_xor(sum, 16);
    sum += __shfl_xor(sum, 32);
    l_run = l_run * alpha + sum;
    m_run = mnew;
    // pack P to bf16 and redistribute: dst lane (li,g) needs j = g*8..g*8+7.
    // source group s0=(2g)&3 supplies first 4 j, s1=(2g+1)&3 next 4;
    // take p0-words if g<2 else p1-words.
    u32 P0a = pk2(p0[0], p0[1]), P0b = pk2(p0[2], p0[3]);
    u32 P1a = pk2(p1[0], p1[1]), P1b = pk2(p1[2], p1[3]);
    int s0 = ((2 * g) & 3) * 16 + li;
    int s1 = ((2 * g + 1) & 3) * 16 + li;
    u32 a0 = (u32)__shfl((int)P0a, s0);
    u32 a1 = (u32)__shfl((int)P0b, s0);
    u32 a2 = (u32)__shfl((int)P0a, s1);
    u32 a3 = (u32)__shfl((int)P0b, s1);
    u32 b0 = (u32)__shfl((int)P1a, s0);
    u32 b1 = (u32)__shfl((int)P1b, s0);
    u32 b2 = (u32)__shfl((int)P1a, s1);
    u32 b3 = (u32)__shfl((int)P1b, s1);
    union { uint4 u4; bf16x8 v; } pf;
    bool hi = g >= 2;
    pf.u4.x = hi ? b0 : a0;
    pf.u4.y = hi ? b1 : a1;
    pf.u4.z = hi ? b2 : a2;
    pf.u4.w = hi ? b3 : a3;
#pragma unroll
    for (int ct = 0; ct < 8; ++ct) {
      bf16x8 vf = *(const bf16x8*)(vbb + ((size_t)(ct * 16 + li)) * 4096 + kv0 + g * 8);
      f32x4 o = ot[ct];
      o[0] *= alpha; o[1] *= alpha; o[2] *= alpha; o[3] *= alpha;
      ot[ct] = __builtin_amdgcn_mfma_f32_16x16x32_bf16(vf, pf.v, o, 0, 0, 0);
    }
  }
  float invl = 1.f / l_run;
  float g0 = gamma[0];
#pragma unroll
  for (int ct = 0; ct < 8; ++ct) {
#pragma unroll
    for (int r = 0; r < 4; ++r) {
      int c = ct * 16 + g * 4 + r;
      size_t adr = (((size_t)b * 128) + c) * 4096 + q0 + li;
      out[adr] = g0 * ot[ct][r] * invl + xp[adr];
    }
  }
}

// ---------------------------------------------------------------------------
extern "C" void kernel_launch(void* const* d_in, const int* in_sizes, int n_in,
                              void* d_out, int out_size, void* d_ws, size_t ws_size,
                              hipStream_t stream) {
  const float* x     = (const float*)d_in[0];
  const float* Wq    = (const float*)d_in[1];
  const float* bq    = (const float*)d_in[2];
  const float* Wk    = (const float*)d_in[3];
  const float* bk    = (const float*)d_in[4];
  const float* Wv    = (const float*)d_in[5];
  const float* bv    = (const float*)d_in[6];
  const float* gamma = (const float*)d_in[7];
  const float* pos   = (const float*)d_in[8];
  float* out = (float*)d_out;

  char* ws = (char*)d_ws;
  float* xp  = (float*)ws;                          //  8,388,608 B  f32 [4][128][4096]
  u16* xpT   = (u16*)(ws + 8388608);                //  4,194,304 B  bf16 [4][4096][128]
  u16* qw    = (u16*)(ws + 12582912);               //  1,048,576 B  bf16 [4][4096][32]
  u16* kw    = (u16*)(ws + 13631488);               //  1,048,576 B  bf16 [4][4096][32]
  u16* vw    = (u16*)(ws + 14680064);               //  4,194,304 B  bf16 [4][128][4096]
  u16* wc    = (u16*)(ws + 18874368);               //     49,152 B  bf16 [192][128]
  float* bc  = (float*)(ws + 18923520);             //        768 B  f32 [192]

  k_prep<<<dim3(64, 2, 4), 256, 0, stream>>>(x, pos, xp, xpT);
  k_wcat<<<96, 256, 0, stream>>>(Wq, bq, Wk, bk, Wv, bv, wc, bc);
  k_proj<<<dim3(64, 4), 256, 0, stream>>>(xpT, wc, bc, qw, kw, vw);
  k_attn<<<dim3(64, 4), 256, 0, stream>>>(qw, kw, vw, xp, gamma, out);
}